// Round 1
// baseline (280.536 us; speedup 1.0000x reference)
//
#include <hip/hip_runtime.h>

#define B 4
#define V 8192
#define F 16384
#define P 4
#define E 2048
#define NPAIR (B*P)

// ws layout (float indices)
#define WS_PTS   0                       // B*P*V*2 = 262144 floats (pts, float2)
#define WS_CHAMY 262144                  // NPAIR*E = 32768 floats (min bits, uint-ordered)
#define WS_CHAMX 294912                  // NPAIR = 16 accum
#define WS_VOLX  294928                  // B
#define WS_VOLY  294932                  // B
#define WS_LSQ   294936                  // B

__device__ __forceinline__ float block_sum(float v, float* sred) {
    #pragma unroll
    for (int off = 32; off; off >>= 1) v += __shfl_down(v, off, 64);
    int w = threadIdx.x >> 6, l = threadIdx.x & 63;
    if (l == 0) sred[w] = v;
    __syncthreads();
    float r = 0.f;
    if (threadIdx.x == 0) {
        r = sred[0];
        for (int i = 1; i < ((int)blockDim.x >> 6); ++i) r += sred[i];
    }
    __syncthreads();
    return r;  // valid on thread 0 only
}

__global__ void k_init(float* __restrict__ ws) {
    int i = blockIdx.x * 256 + threadIdx.x;
    if (i < NPAIR * E) ((unsigned*)(ws + WS_CHAMY))[i] = 0x7F800000u;  // +inf
    if (i < 28) ws[WS_CHAMX + i] = 0.f;
}

__global__ void __launch_bounds__(256) k_proj(const float* __restrict__ xs,
                                              const float* __restrict__ y,
                                              const float* __restrict__ pm,
                                              float* __restrict__ ws) {
    __shared__ float spm[48];
    __shared__ float sred[4];
    int tid = threadIdx.x;
    if (tid < 48) spm[tid] = pm[tid];
    __syncthreads();
    int b = blockIdx.x >> 5;                 // V/256 = 32 blocks per batch
    int v = ((blockIdx.x & 31) << 8) + tid;
    size_t base = ((size_t)b * V + v) * 3;
    float y0 = y[base], y1 = y[base + 1], y2 = y[base + 2];
    float x0 = xs[base], x1 = xs[base + 1], x2 = xs[base + 2];
    float d0 = x0 - y0, d1 = x1 - y1, d2 = x2 - y2;
    float lsq = d0 * d0 + d1 * d1 + d2 * d2;

    float2* pts = (float2*)(ws + WS_PTS);
    #pragma unroll
    for (int p = 0; p < P; ++p) {
        const float* m = spm + p * 12;
        float xw = m[0] * y0 + m[1] * y1 + m[2]  * y2 + m[3];
        float yw = m[4] * y0 + m[5] * y1 + m[6]  * y2 + m[7];
        float w  = m[8] * y0 + m[9] * y1 + m[10] * y2 + m[11];
        pts[(size_t)(b * P + p) * V + v] = make_float2(xw / w, yw / w);
    }

    float s = block_sum(lsq, sred);
    if (tid == 0) atomicAdd(ws + WS_LSQ + b, s);
}

__device__ __forceinline__ float facevol(const float* __restrict__ vb,
                                         int i0, int i1, int i2) {
    float a0 = vb[i0 * 3], a1 = vb[i0 * 3 + 1], a2 = vb[i0 * 3 + 2];
    float b0 = vb[i1 * 3], b1 = vb[i1 * 3 + 1], b2 = vb[i1 * 3 + 2];
    float c0 = vb[i2 * 3], c1 = vb[i2 * 3 + 1], c2 = vb[i2 * 3 + 2];
    float cx = a1 * b2 - a2 * b1;
    float cy = a2 * b0 - a0 * b2;
    float cz = a0 * b1 - a1 * b0;
    return (cx * c0 + cy * c1 + cz * c2) * (1.0f / 6.0f);
}

__global__ void __launch_bounds__(256) k_vol(const float* __restrict__ xs,
                                             const float* __restrict__ y,
                                             const int* __restrict__ faces,
                                             float* __restrict__ ws) {
    __shared__ float sred[4];
    int tid = threadIdx.x;
    int b = blockIdx.x >> 6;                 // F/256 = 64 blocks per batch
    int f = ((blockIdx.x & 63) << 8) + tid;
    size_t fb = ((size_t)b * F + f) * 3;
    int i0 = faces[fb], i1 = faces[fb + 1], i2 = faces[fb + 2];
    const float* xb = xs + (size_t)b * V * 3;
    const float* yb = y  + (size_t)b * V * 3;
    float fvx = facevol(xb, i0, i1, i2);
    float fvy = facevol(yb, i0, i1, i2);
    float sx = block_sum(fvx, sred);
    float sy = block_sum(fvy, sred);
    if (tid == 0) {
        atomicAdd(ws + WS_VOLX + b, sx);
        atomicAdd(ws + WS_VOLY + b, sy);
    }
}

// one block = (pair, v-chunk of 256); stage all E edges in LDS; thread = one v
__global__ void __launch_bounds__(256) k_chamx(const float* __restrict__ edgemaps,
                                               float* __restrict__ ws) {
    __shared__ float4 se[E / 2];             // 2048 edge pts = 16 KB
    __shared__ float sred[4];
    int tid = threadIdx.x;
    int pair = blockIdx.x >> 5;              // 32 v-chunks
    int vchunk = blockIdx.x & 31;
    const float4* eg = (const float4*)edgemaps + (size_t)pair * (E / 2);
    #pragma unroll
    for (int i = 0; i < (E / 2) / 256; ++i) se[tid + i * 256] = eg[tid + i * 256];
    __syncthreads();

    const float2* pts = (const float2*)(ws + WS_PTS);
    float2 pv = pts[(size_t)pair * V + vchunk * 256 + tid];
    float m = 3.4e38f;
    #pragma unroll 8
    for (int i = 0; i < E / 2; ++i) {
        float4 e = se[i];
        float dx0 = pv.x - e.x, dy0 = pv.y - e.y;
        float dx1 = pv.x - e.z, dy1 = pv.y - e.w;
        float d0 = dx0 * dx0 + dy0 * dy0;
        float d1 = dx1 * dx1 + dy1 * dy1;
        m = fminf(m, fminf(d0, d1));
    }
    float s = block_sum(m, sred);
    if (tid == 0) atomicAdd(ws + WS_CHAMX + pair, s);
}

// one block = (pair, e-chunk of 256, v-chunk of 2048); stage pts chunk in LDS
__global__ void __launch_bounds__(256) k_chamy(const float* __restrict__ edgemaps,
                                               float* __restrict__ ws) {
    __shared__ float4 sp[1024];              // 2048 pts = 16 KB
    int tid = threadIdx.x;
    int pair = blockIdx.x >> 5;              // 8 e-chunks x 4 v-chunks
    int echunk = (blockIdx.x >> 2) & 7;
    int vchunk = blockIdx.x & 3;
    const float4* pg = (const float4*)(ws + WS_PTS) + (size_t)pair * (V / 2) + vchunk * 1024;
    #pragma unroll
    for (int i = 0; i < 4; ++i) sp[tid + i * 256] = pg[tid + i * 256];
    __syncthreads();

    int e = echunk * 256 + tid;
    const float2* eg = (const float2*)edgemaps + (size_t)pair * E;
    float2 ev = eg[e];
    float m = 3.4e38f;
    #pragma unroll 8
    for (int i = 0; i < 1024; ++i) {
        float4 q = sp[i];
        float dx0 = q.x - ev.x, dy0 = q.y - ev.y;
        float dx1 = q.z - ev.x, dy1 = q.w - ev.y;
        float d0 = dx0 * dx0 + dy0 * dy0;
        float d1 = dx1 * dx1 + dy1 * dy1;
        m = fminf(m, fminf(d0, d1));
    }
    atomicMin((unsigned*)(ws + WS_CHAMY) + (size_t)pair * E + e, __float_as_uint(m));
}

__global__ void __launch_bounds__(256) k_final(float* __restrict__ ws,
                                               float* __restrict__ out) {
    __shared__ float chamy_s[NPAIR];
    __shared__ float sred[4];
    int tid = threadIdx.x;
    const float* mins = ws + WS_CHAMY;       // uint-min bits are valid floats (>=0)
    for (int pair = 0; pair < NPAIR; ++pair) {
        float s = 0.f;
        for (int i = tid; i < E; i += 256) s += mins[(size_t)pair * E + i];
        float t = block_sum(s, sred);
        if (tid == 0) chamy_s[pair] = t * (1.0f / E);
        __syncthreads();
    }
    if (tid < B) {
        int b = tid;
        float c = 0.f;
        for (int p = 0; p < P; ++p) {
            int pair = b * P + p;
            c += ws[WS_CHAMX + pair] * (1.0f / V) + chamy_s[pair];
        }
        c *= (1.0f / P);
        float vx = fabsf(ws[WS_VOLX + b]);
        float vy = fabsf(ws[WS_VOLY + b]);
        float dv = vy - vx;
        out[b] = c + ws[WS_LSQ + b] + dv * dv;
    }
}

extern "C" void kernel_launch(void* const* d_in, const int* in_sizes, int n_in,
                              void* d_out, int out_size, void* d_ws, size_t ws_size,
                              hipStream_t stream) {
    const float* xs    = (const float*)d_in[0];
    const float* y     = (const float*)d_in[1];
    const float* pm    = (const float*)d_in[2];
    const float* em    = (const float*)d_in[3];
    const int*   faces = (const int*)d_in[4];
    float* ws  = (float*)d_ws;
    float* out = (float*)d_out;

    hipLaunchKernelGGL(k_init,  dim3(128),          dim3(256), 0, stream, ws);
    hipLaunchKernelGGL(k_proj,  dim3(B * V / 256),  dim3(256), 0, stream, xs, y, pm, ws);
    hipLaunchKernelGGL(k_vol,   dim3(B * F / 256),  dim3(256), 0, stream, xs, y, faces, ws);
    hipLaunchKernelGGL(k_chamx, dim3(NPAIR * 32),   dim3(256), 0, stream, em, ws);
    hipLaunchKernelGGL(k_chamy, dim3(NPAIR * 32),   dim3(256), 0, stream, em, ws);
    hipLaunchKernelGGL(k_final, dim3(1),            dim3(256), 0, stream, ws, out);
}

// Round 2
// 187.321 us; speedup vs baseline: 1.4976x; 1.4976x over previous
//
#include <hip/hip_runtime.h>

#define B 4
#define V 8192
#define F 16384
#define P 4
#define E 2048
#define NPAIR (B*P)
#define ESPLIT 4
#define VSPLIT 8

// ws layout (float indices)
#define WS_PTS   0                        // NPAIR*V float4 (px,py,|p|^2,0) = 524288 floats
#define WS_ER    524288                   // NPAIR*E float4 (ex,ey,|e|^2,0) = 131072 floats
#define WS_VMIN  655360                   // NPAIR*V uint-min bits (d2 >= 0)
#define WS_EMIN  786432                   // NPAIR*E uint-min bits
#define WS_CX    819200                   // NPAIR
#define WS_CY    819216                   // NPAIR
#define WS_VOLX  819232                   // B
#define WS_VOLY  819236                   // B
#define WS_LSQ   819240                   // B  (total 819244 floats = 3.28 MB)

#define INFBITS 0x7F800000u

__device__ __forceinline__ float block_sum(float v, float* sred) {
    #pragma unroll
    for (int off = 32; off; off >>= 1) v += __shfl_down(v, off, 64);
    int w = threadIdx.x >> 6, l = threadIdx.x & 63;
    if (l == 0) sred[w] = v;
    __syncthreads();
    float r = 0.f;
    if (threadIdx.x == 0) {
        r = sred[0];
        for (int i = 1; i < ((int)blockDim.x >> 6); ++i) r += sred[i];
    }
    __syncthreads();
    return r;  // valid on thread 0 only
}

// init mins to +inf, accums to 0, and build ER (edges with |e|^2)
__global__ void __launch_bounds__(256) k_init(const float* __restrict__ em,
                                              float* __restrict__ ws) {
    int i = blockIdx.x * 256 + threadIdx.x;          // 512 blocks -> 131072 threads
    ((unsigned*)(ws + WS_VMIN))[i] = INFBITS;
    if (i < NPAIR * E) {
        ((unsigned*)(ws + WS_EMIN))[i] = INFBITS;
        float2 e = ((const float2*)em)[i];
        ((float4*)(ws + WS_ER))[i] = make_float4(e.x, e.y, e.x * e.x + e.y * e.y, 0.f);
    }
    if (i < 44) ws[WS_CX + i] = 0.f;
}

__global__ void __launch_bounds__(256) k_proj(const float* __restrict__ xs,
                                              const float* __restrict__ y,
                                              const float* __restrict__ pm,
                                              float* __restrict__ ws) {
    __shared__ float spm[48];
    __shared__ float sred[4];
    int tid = threadIdx.x;
    if (tid < 48) spm[tid] = pm[tid];
    __syncthreads();
    int b = blockIdx.x >> 5;                 // V/256 = 32 blocks per batch
    int v = ((blockIdx.x & 31) << 8) + tid;
    size_t base = ((size_t)b * V + v) * 3;
    float y0 = y[base], y1 = y[base + 1], y2 = y[base + 2];
    float x0 = xs[base], x1 = xs[base + 1], x2 = xs[base + 2];
    float d0 = x0 - y0, d1 = x1 - y1, d2 = x2 - y2;
    float lsq = d0 * d0 + d1 * d1 + d2 * d2;

    float4* pts = (float4*)(ws + WS_PTS);
    #pragma unroll
    for (int p = 0; p < P; ++p) {
        const float* m = spm + p * 12;
        float xw = m[0] * y0 + m[1] * y1 + m[2]  * y2 + m[3];
        float yw = m[4] * y0 + m[5] * y1 + m[6]  * y2 + m[7];
        float w  = m[8] * y0 + m[9] * y1 + m[10] * y2 + m[11];
        float px = xw / w, py = yw / w;
        pts[(size_t)(b * P + p) * V + v] = make_float4(px, py, px * px + py * py, 0.f);
    }

    float s = block_sum(lsq, sred);
    if (tid == 0) atomicAdd(ws + WS_LSQ + b, s);
}

__device__ __forceinline__ float facevol(const float* __restrict__ vb,
                                         int i0, int i1, int i2) {
    float a0 = vb[i0 * 3], a1 = vb[i0 * 3 + 1], a2 = vb[i0 * 3 + 2];
    float b0 = vb[i1 * 3], b1 = vb[i1 * 3 + 1], b2 = vb[i1 * 3 + 2];
    float c0 = vb[i2 * 3], c1 = vb[i2 * 3 + 1], c2 = vb[i2 * 3 + 2];
    float cx = a1 * b2 - a2 * b1;
    float cy = a2 * b0 - a0 * b2;
    float cz = a0 * b1 - a1 * b0;
    return (cx * c0 + cy * c1 + cz * c2) * (1.0f / 6.0f);
}

__global__ void __launch_bounds__(256) k_vol(const float* __restrict__ xs,
                                             const float* __restrict__ y,
                                             const int* __restrict__ faces,
                                             float* __restrict__ ws) {
    __shared__ float sred[4];
    int tid = threadIdx.x;
    int b = blockIdx.x >> 6;                 // F/256 = 64 blocks per batch
    int f = ((blockIdx.x & 63) << 8) + tid;
    size_t fb = ((size_t)b * F + f) * 3;
    int i0 = faces[fb], i1 = faces[fb + 1], i2 = faces[fb + 2];
    const float* xb = xs + (size_t)b * V * 3;
    const float* yb = y  + (size_t)b * V * 3;
    float fvx = facevol(xb, i0, i1, i2);
    float fvy = facevol(yb, i0, i1, i2);
    float sx = block_sum(fvx, sred);
    float sy = block_sum(fvy, sred);
    if (tid == 0) {
        atomicAdd(ws + WS_VOLX + b, sx);
        atomicAdd(ws + WS_VOLY + b, sy);
    }
}

// block = (pair, v-chunk of 256, e-chunk of E/ESPLIT). thread = one v.
// edge reads are wave-uniform -> scalar loads.
__global__ void __launch_bounds__(256) k_chamx(float* __restrict__ ws) {
    int tid = threadIdx.x;
    int blk = blockIdx.x;                    // NPAIR * 32 * ESPLIT = 2048
    int pair = blk >> 7;
    int vchunk = (blk >> 2) & 31;
    int echunk = blk & 3;
    float4 pv = ((const float4*)(ws + WS_PTS))[(size_t)pair * V + vchunk * 256 + tid];
    float px2 = -2.f * pv.x, py2 = -2.f * pv.y;
    const float4* er = (const float4*)(ws + WS_ER) + (size_t)pair * E + echunk * (E / ESPLIT);

    float m0 = 3.4e38f, m1 = 3.4e38f, m2 = 3.4e38f, m3 = 3.4e38f;
    #pragma unroll 4
    for (int i = 0; i < E / ESPLIT; i += 4) {
        float4 e0 = er[i], e1 = er[i + 1], e2 = er[i + 2], e3 = er[i + 3];
        m0 = fminf(m0, fmaf(px2, e0.x, fmaf(py2, e0.y, e0.z)));
        m1 = fminf(m1, fmaf(px2, e1.x, fmaf(py2, e1.y, e1.z)));
        m2 = fminf(m2, fmaf(px2, e2.x, fmaf(py2, e2.y, e2.z)));
        m3 = fminf(m3, fmaf(px2, e3.x, fmaf(py2, e3.y, e3.z)));
    }
    float m = fminf(fminf(m0, m1), fminf(m2, m3)) + pv.z;   // + |p|^2 -> d2 >= 0
    atomicMin((unsigned*)(ws + WS_VMIN) + (size_t)pair * V + vchunk * 256 + tid,
              __float_as_uint(m));
}

// block = (pair, e-chunk of 256, v-chunk of V/VSPLIT). thread = one e.
// point reads are wave-uniform -> scalar loads.
__global__ void __launch_bounds__(256) k_chamy(float* __restrict__ ws) {
    int tid = threadIdx.x;
    int blk = blockIdx.x;                    // NPAIR * 8 * VSPLIT = 1024
    int pair = blk >> 6;
    int echunk = (blk >> 3) & 7;
    int vchunk = blk & 7;
    float4 ev = ((const float4*)(ws + WS_ER))[(size_t)pair * E + echunk * 256 + tid];
    float ex2 = -2.f * ev.x, ey2 = -2.f * ev.y;
    const float4* pts = (const float4*)(ws + WS_PTS) + (size_t)pair * V + vchunk * (V / VSPLIT);

    float m0 = 3.4e38f, m1 = 3.4e38f, m2 = 3.4e38f, m3 = 3.4e38f;
    #pragma unroll 4
    for (int i = 0; i < V / VSPLIT; i += 4) {
        float4 p0 = pts[i], p1 = pts[i + 1], p2 = pts[i + 2], p3 = pts[i + 3];
        m0 = fminf(m0, fmaf(ex2, p0.x, fmaf(ey2, p0.y, p0.z)));
        m1 = fminf(m1, fmaf(ex2, p1.x, fmaf(ey2, p1.y, p1.z)));
        m2 = fminf(m2, fmaf(ex2, p2.x, fmaf(ey2, p2.y, p2.z)));
        m3 = fminf(m3, fmaf(ex2, p3.x, fmaf(ey2, p3.y, p3.z)));
    }
    float m = fminf(fminf(m0, m1), fminf(m2, m3)) + ev.z;   // + |e|^2 -> d2 >= 0
    atomicMin((unsigned*)(ws + WS_EMIN) + (size_t)pair * E + echunk * 256 + tid,
              __float_as_uint(m));
}

// 640 blocks: [0,512) sum VMIN/V into CX, [512,640) sum EMIN/E into CY
__global__ void __launch_bounds__(256) k_red(float* __restrict__ ws) {
    __shared__ float sred[4];
    int tid = threadIdx.x;
    int blk = blockIdx.x;
    float val;
    int pair;
    float* dst;
    if (blk < 512) {
        int idx = blk * 256 + tid;
        pair = blk >> 5;                     // V/256 = 32 blocks per pair
        val = ws[WS_VMIN + idx] * (1.0f / V);
        dst = ws + WS_CX + pair;
    } else {
        int idx = (blk - 512) * 256 + tid;
        pair = (blk - 512) >> 3;             // E/256 = 8 blocks per pair
        val = ws[WS_EMIN + idx] * (1.0f / E);
        dst = ws + WS_CY + pair;
    }
    float s = block_sum(val, sred);
    if (tid == 0) atomicAdd(dst, s);
}

__global__ void k_out(float* __restrict__ ws, float* __restrict__ out) {
    int b = threadIdx.x;
    if (b < B) {
        float c = 0.f;
        for (int p = 0; p < P; ++p) {
            int pair = b * P + p;
            c += ws[WS_CX + pair] + ws[WS_CY + pair];
        }
        c *= (1.0f / P);
        float vx = fabsf(ws[WS_VOLX + b]);
        float vy = fabsf(ws[WS_VOLY + b]);
        float dv = vy - vx;
        out[b] = c + ws[WS_LSQ + b] + dv * dv;
    }
}

extern "C" void kernel_launch(void* const* d_in, const int* in_sizes, int n_in,
                              void* d_out, int out_size, void* d_ws, size_t ws_size,
                              hipStream_t stream) {
    const float* xs    = (const float*)d_in[0];
    const float* y     = (const float*)d_in[1];
    const float* pm    = (const float*)d_in[2];
    const float* em    = (const float*)d_in[3];
    const int*   faces = (const int*)d_in[4];
    float* ws  = (float*)d_ws;
    float* out = (float*)d_out;

    hipLaunchKernelGGL(k_init,  dim3(512),                  dim3(256), 0, stream, em, ws);
    hipLaunchKernelGGL(k_proj,  dim3(B * V / 256),          dim3(256), 0, stream, xs, y, pm, ws);
    hipLaunchKernelGGL(k_vol,   dim3(B * F / 256),          dim3(256), 0, stream, xs, y, faces, ws);
    hipLaunchKernelGGL(k_chamx, dim3(NPAIR * 32 * ESPLIT),  dim3(256), 0, stream, ws);
    hipLaunchKernelGGL(k_chamy, dim3(NPAIR * 8 * VSPLIT),   dim3(256), 0, stream, ws);
    hipLaunchKernelGGL(k_red,   dim3(640),                  dim3(256), 0, stream, ws);
    hipLaunchKernelGGL(k_out,   dim3(1),                    dim3(64),  0, stream, ws, out);
}

// Round 3
// 123.847 us; speedup vs baseline: 2.2652x; 1.5125x over previous
//
#include <hip/hip_runtime.h>

#define B 4
#define V 8192
#define F 16384
#define P 4
#define E 2048
#define NPAIR (B*P)

// ws layout (float indices)
#define WS_PTS   0                        // NPAIR*V float4 (px,py,|p|^2,0) = 524288 floats
#define WS_ER    524288                   // NPAIR*E float4 (ex,ey,|e|^2,0) = 131072 floats
#define WS_VMIN  655360                   // NPAIR*V uint-min bits (d2 >= 0)
#define WS_EMIN  786432                   // NPAIR*E uint-min bits
#define WS_CX    819200                   // NPAIR
#define WS_CY    819216                   // NPAIR
#define WS_VOLX  819232                   // B
#define WS_VOLY  819236                   // B
#define WS_LSQ   819240                   // B  (total 819244 floats = 3.28 MB)

#define INFBITS 0x7F800000u

__device__ __forceinline__ float block_sum(float v, float* sred) {
    #pragma unroll
    for (int off = 32; off; off >>= 1) v += __shfl_down(v, off, 64);
    int w = threadIdx.x >> 6, l = threadIdx.x & 63;
    if (l == 0) sred[w] = v;
    __syncthreads();
    float r = 0.f;
    if (threadIdx.x == 0) {
        r = sred[0];
        for (int i = 1; i < ((int)blockDim.x >> 6); ++i) r += sred[i];
    }
    __syncthreads();
    return r;  // valid on thread 0 only
}

// init mins to +inf, build ER (edges with |e|^2), zero accums. 512 blocks.
__global__ void __launch_bounds__(256) k_init(const float* __restrict__ em,
                                              float* __restrict__ ws) {
    int i = blockIdx.x * 256 + threadIdx.x;          // 131072 threads
    ((unsigned*)(ws + WS_VMIN))[i] = INFBITS;
    if (i < NPAIR * E) {
        ((unsigned*)(ws + WS_EMIN))[i] = INFBITS;
        float2 e = ((const float2*)em)[i];
        ((float4*)(ws + WS_ER))[i] = make_float4(e.x, e.y, e.x * e.x + e.y * e.y, 0.f);
    }
    if (i < 44) ws[WS_CX + i] = 0.f;
}

__global__ void __launch_bounds__(256) k_proj(const float* __restrict__ xs,
                                              const float* __restrict__ y,
                                              const float* __restrict__ pm,
                                              float* __restrict__ ws) {
    __shared__ float spm[48];
    __shared__ float sred[4];
    int tid = threadIdx.x;
    if (tid < 48) spm[tid] = pm[tid];
    __syncthreads();
    int b = blockIdx.x >> 5;                 // V/256 = 32 blocks per batch
    int v = ((blockIdx.x & 31) << 8) + tid;
    size_t base = ((size_t)b * V + v) * 3;
    float y0 = y[base], y1 = y[base + 1], y2 = y[base + 2];
    float x0 = xs[base], x1 = xs[base + 1], x2 = xs[base + 2];
    float d0 = x0 - y0, d1 = x1 - y1, d2 = x2 - y2;
    float lsq = d0 * d0 + d1 * d1 + d2 * d2;

    float4* pts = (float4*)(ws + WS_PTS);
    #pragma unroll
    for (int p = 0; p < P; ++p) {
        const float* m = spm + p * 12;
        float xw = m[0] * y0 + m[1] * y1 + m[2]  * y2 + m[3];
        float yw = m[4] * y0 + m[5] * y1 + m[6]  * y2 + m[7];
        float w  = m[8] * y0 + m[9] * y1 + m[10] * y2 + m[11];
        float px = xw / w, py = yw / w;
        pts[(size_t)(b * P + p) * V + v] = make_float4(px, py, px * px + py * py, 0.f);
    }

    float s = block_sum(lsq, sred);
    if (tid == 0) atomicAdd(ws + WS_LSQ + b, s);
}

__device__ __forceinline__ float facevol(const float* __restrict__ vb,
                                         int i0, int i1, int i2) {
    float a0 = vb[i0 * 3], a1 = vb[i0 * 3 + 1], a2 = vb[i0 * 3 + 2];
    float b0 = vb[i1 * 3], b1 = vb[i1 * 3 + 1], b2 = vb[i1 * 3 + 2];
    float c0 = vb[i2 * 3], c1 = vb[i2 * 3 + 1], c2 = vb[i2 * 3 + 2];
    float cx = a1 * b2 - a2 * b1;
    float cy = a2 * b0 - a0 * b2;
    float cz = a0 * b1 - a1 * b0;
    return (cx * c0 + cy * c1 + cz * c2) * (1.0f / 6.0f);
}

__global__ void __launch_bounds__(256) k_vol(const float* __restrict__ xs,
                                             const float* __restrict__ y,
                                             const int* __restrict__ faces,
                                             float* __restrict__ ws) {
    __shared__ float sred[4];
    int tid = threadIdx.x;
    int b = blockIdx.x >> 6;                 // F/256 = 64 blocks per batch
    int f = ((blockIdx.x & 63) << 8) + tid;
    size_t fb = ((size_t)b * F + f) * 3;
    int i0 = faces[fb], i1 = faces[fb + 1], i2 = faces[fb + 2];
    const float* xb = xs + (size_t)b * V * 3;
    const float* yb = y  + (size_t)b * V * 3;
    float fvx = facevol(xb, i0, i1, i2);
    float fvy = facevol(yb, i0, i1, i2);
    float sx = block_sum(fvx, sred);
    float sy = block_sum(fvy, sred);
    if (tid == 0) {
        atomicAdd(ws + WS_VOLX + b, sx);
        atomicAdd(ws + WS_VOLY + b, sy);
    }
}

// min over e for each v. Thread owns 8 v's in registers; edges stream through
// LDS with wave-uniform broadcast ds_read_b128 (1 read per 24 VALU ops).
// grid = NPAIR(16) * VCH(4) * ECH(8) = 512 blocks
__global__ void __launch_bounds__(256) k_chamx(float* __restrict__ ws) {
    __shared__ float4 se[256];               // 4 KB edge chunk
    int tid = threadIdx.x;
    int blk = blockIdx.x;
    int pair = blk >> 5;
    int vch = (blk >> 3) & 3;
    int ech = blk & 7;

    se[tid] = ((const float4*)(ws + WS_ER))[(size_t)pair * E + ech * 256 + tid];

    const float4* pts = (const float4*)(ws + WS_PTS) + (size_t)pair * V + vch * 2048 + tid;
    float px2[8], py2[8], pz[8], mn[8];
    #pragma unroll
    for (int k = 0; k < 8; ++k) {
        float4 p = pts[k * 256];
        px2[k] = -2.f * p.x; py2[k] = -2.f * p.y; pz[k] = p.z;
        mn[k] = 3.4e38f;
    }
    __syncthreads();

    #pragma unroll 4
    for (int i = 0; i < 256; ++i) {
        float4 e = se[i];                    // broadcast: all lanes same address
        #pragma unroll
        for (int k = 0; k < 8; ++k)
            mn[k] = fminf(mn[k], fmaf(px2[k], e.x, fmaf(py2[k], e.y, e.z)));
    }

    unsigned* vmin = (unsigned*)(ws + WS_VMIN) + (size_t)pair * V + vch * 2048 + tid;
    #pragma unroll
    for (int k = 0; k < 8; ++k)
        atomicMin(vmin + k * 256, __float_as_uint(mn[k] + pz[k]));
}

// min over v for each e. Thread owns 8 e's (full E per block); points stream
// through LDS broadcast.  grid = NPAIR(16) * VCH2(32) = 512 blocks
__global__ void __launch_bounds__(256) k_chamy(float* __restrict__ ws) {
    __shared__ float4 sp[256];               // 4 KB point chunk
    int tid = threadIdx.x;
    int blk = blockIdx.x;
    int pair = blk >> 5;
    int vch = blk & 31;

    sp[tid] = ((const float4*)(ws + WS_PTS))[(size_t)pair * V + vch * 256 + tid];

    const float4* er = (const float4*)(ws + WS_ER) + (size_t)pair * E + tid;
    float ex2[8], ey2[8], ez[8], mn[8];
    #pragma unroll
    for (int k = 0; k < 8; ++k) {
        float4 e = er[k * 256];
        ex2[k] = -2.f * e.x; ey2[k] = -2.f * e.y; ez[k] = e.z;
        mn[k] = 3.4e38f;
    }
    __syncthreads();

    #pragma unroll 4
    for (int i = 0; i < 256; ++i) {
        float4 p = sp[i];                    // broadcast
        #pragma unroll
        for (int k = 0; k < 8; ++k)
            mn[k] = fminf(mn[k], fmaf(ex2[k], p.x, fmaf(ey2[k], p.y, p.z)));
    }

    unsigned* emin = (unsigned*)(ws + WS_EMIN) + (size_t)pair * E + tid;
    #pragma unroll
    for (int k = 0; k < 8; ++k)
        atomicMin(emin + k * 256, __float_as_uint(mn[k] + ez[k]));
}

// 640 blocks: [0,512) sum VMIN/V into CX, [512,640) sum EMIN/E into CY
__global__ void __launch_bounds__(256) k_red(float* __restrict__ ws) {
    __shared__ float sred[4];
    int tid = threadIdx.x;
    int blk = blockIdx.x;
    float val;
    float* dst;
    if (blk < 512) {
        int idx = blk * 256 + tid;
        val = ws[WS_VMIN + idx] * (1.0f / V);
        dst = ws + WS_CX + (blk >> 5);
    } else {
        int idx = (blk - 512) * 256 + tid;
        val = ws[WS_EMIN + idx] * (1.0f / E);
        dst = ws + WS_CY + ((blk - 512) >> 3);
    }
    float s = block_sum(val, sred);
    if (tid == 0) atomicAdd(dst, s);
}

__global__ void k_out(float* __restrict__ ws, float* __restrict__ out) {
    int b = threadIdx.x;
    if (b < B) {
        float c = 0.f;
        for (int p = 0; p < P; ++p) {
            int pair = b * P + p;
            c += ws[WS_CX + pair] + ws[WS_CY + pair];
        }
        c *= (1.0f / P);
        float vx = fabsf(ws[WS_VOLX + b]);
        float vy = fabsf(ws[WS_VOLY + b]);
        float dv = vy - vx;
        out[b] = c + ws[WS_LSQ + b] + dv * dv;
    }
}

extern "C" void kernel_launch(void* const* d_in, const int* in_sizes, int n_in,
                              void* d_out, int out_size, void* d_ws, size_t ws_size,
                              hipStream_t stream) {
    const float* xs    = (const float*)d_in[0];
    const float* y     = (const float*)d_in[1];
    const float* pm    = (const float*)d_in[2];
    const float* em    = (const float*)d_in[3];
    const int*   faces = (const int*)d_in[4];
    float* ws  = (float*)d_ws;
    float* out = (float*)d_out;

    hipLaunchKernelGGL(k_init,  dim3(512),         dim3(256), 0, stream, em, ws);
    hipLaunchKernelGGL(k_proj,  dim3(B * V / 256), dim3(256), 0, stream, xs, y, pm, ws);
    hipLaunchKernelGGL(k_vol,   dim3(B * F / 256), dim3(256), 0, stream, xs, y, faces, ws);
    hipLaunchKernelGGL(k_chamx, dim3(512),         dim3(256), 0, stream, ws);
    hipLaunchKernelGGL(k_chamy, dim3(512),         dim3(256), 0, stream, ws);
    hipLaunchKernelGGL(k_red,   dim3(640),         dim3(256), 0, stream, ws);
    hipLaunchKernelGGL(k_out,   dim3(1),           dim3(64),  0, stream, ws, out);
}